// Round 21
// baseline (236.035 us; speedup 1.0000x reference)
//
#include <hip/hip_runtime.h>
#include <hip/hip_bf16.h>
#include <math.h>

// VQ quantizer: bf16-MFMA prefilter (TWO passes, r7-proven structure) + fp32-chain
// exact rescore.  Exact semantics (validated r2/r4/r6): dist = fl32(fl32(r2+e2) -
// 2*fma_chain(x.e)), argmin first-min-wins.
// Pass 1: GEMM + per-row atomicMin(rowMinU) [fire-and-forget]. Pass 2: identical
// GEMM, capture c with s <= FINAL_min + M (deterministic set; M=8e-4 >= 2delta
// ~3.6e-4; E[cands]~10, CAP=56 — r6/r7-proven stats). Exact full-scan fallback.
// Round 21: BK=128 (2 stage/barrier rounds per block instead of 4; 16 in-flight
// global_load_lds per wave) — r7's residual is only 18us, its cost is the 2 GEMMs,
// and the K=256 GEMM is barrier-round-overhead-bound (346 TF vs 874 at large K).
// Outputs (float32 flat): [loss | quantized(8192*256) | indices(8192 as float)]

#define NROWS 8192
#define DDIM  256
#define KCW   8192
#define CAP   56
#define MARGIN 8e-4f

typedef __attribute__((ext_vector_type(8))) short short8;
typedef __attribute__((ext_vector_type(4))) float f32x4;
typedef unsigned int u32;

__device__ inline void async_copy16(void* lds_uniform, const void* gsrc) {
  __builtin_amdgcn_global_load_lds(
      (const __attribute__((address_space(1))) u32*)gsrc,
      (__attribute__((address_space(3))) u32*)lds_uniform, 16, 0, 0);
}

__device__ inline unsigned fmap(float f) {
  unsigned b = __float_as_uint(f);
  return (b & 0x80000000u) ? ~b : (b | 0x80000000u);
}
__device__ inline float funmap(unsigned u) {
  unsigned b = (u & 0x80000000u) ? (u & 0x7FFFFFFFu) : ~u;
  return __uint_as_float(b);
}

// Fused: bf16 cast + e2 (f64->f32, cb rows) + rowMinU/cnt init (z rows).
// rowMinU init = fmap(+inf) = 0xFF800000.
__global__ __launch_bounds__(256) void k_prep_cast(const float* __restrict__ z,
                                                   const float* __restrict__ cb,
                                                   ushort* __restrict__ zb,
                                                   ushort* __restrict__ cbb,
                                                   float* __restrict__ e2f,
                                                   unsigned* __restrict__ rowMinU,
                                                   unsigned* __restrict__ cnt) {
  int t = threadIdx.x, w = t >> 6, lane = t & 63;
  int wid = blockIdx.x * 4 + w;           // 0..16383
  bool isCb = wid >= NROWS;
  int row = isCb ? wid - NROWS : wid;
  const float* src = (isCb ? cb : z) + (size_t)row * DDIM + lane * 4;
  float4 v = *reinterpret_cast<const float4*>(src);
  ushort4 o;
  __hip_bfloat16 bx = __float2bfloat16(v.x); o.x = *(ushort*)&bx;
  __hip_bfloat16 by = __float2bfloat16(v.y); o.y = *(ushort*)&by;
  __hip_bfloat16 bz = __float2bfloat16(v.z); o.z = *(ushort*)&bz;
  __hip_bfloat16 bw = __float2bfloat16(v.w); o.w = *(ushort*)&bw;
  ushort* dst = (isCb ? cbb : zb) + (size_t)row * DDIM + lane * 4;
  *reinterpret_cast<ushort4*>(dst) = o;
  if (isCb) {
    double d = (double)v.x * v.x + (double)v.y * v.y + (double)v.z * v.z + (double)v.w * v.w;
#pragma unroll
    for (int off = 1; off < 64; off <<= 1) d += __shfl_xor(d, off);
    if (lane == 0) e2f[row] = (float)d;
  } else {
    if (lane == 0) { rowMinU[row] = 0xFF800000u; cnt[row] = 0; }
  }
}

// 128x128 tile MFMA GEMM, BK=128 (2 stage rounds), 4 waves each 64x64 output.
// Staging: 64 chunks of 1KB (32 A, 32 B; chunk = 4 rows x 256B half-rows), wave
// owns 16. Source slot pre-swizzled (slot ^ row&7), LDS linear, XOR on ds_read
// (bijective pair, rule #21). 2-way LDS read aliasing only (free, m136).
// PHASE 1: per-row tile-min -> atomicMin(rowMinU), fire-and-forget.
// PHASE 2: capture s <= funmap(final rowMinU) + MARGIN (deterministic set).
template<int PHASE>
__global__ __launch_bounds__(256, 2) void k_score(const ushort* __restrict__ zb,
                                                  const ushort* __restrict__ cbb,
                                                  const float* __restrict__ e2f,
                                                  unsigned* __restrict__ rowMinU,
                                                  unsigned* __restrict__ cnt,
                                                  int* __restrict__ cand) {
  __shared__ ushort Ab[128 * 128];       // 32 KB
  __shared__ ushort Bb[128 * 128];       // 32 KB
  int t = threadIdx.x, w = t >> 6, lane = t & 63;
  int wg = ((blockIdx.x & 7) << 9) | (blockIdx.x >> 3);   // XCD swizzle (4096%8==0)
  int mt = wg >> 6, nt = wg & 63;
  int wm = w >> 1, wn = w & 1;
  int cl = lane & 15, g = lane >> 4;

  int rloc4 = lane >> 4;                 // row within chunk: 0..3
  int slot  = lane & 15;                 // 16B slot within 256B half-row
  const ushort* arow_base = zb  + (size_t)(mt * 128) * DDIM;
  const ushort* brow_base = cbb + (size_t)(nt * 128) * DDIM;

  f32x4 acc[4][4];
#pragma unroll
  for (int m = 0; m < 4; ++m)
#pragma unroll
    for (int n = 0; n < 4; ++n) acc[m][n] = (f32x4){0.f, 0.f, 0.f, 0.f};

  for (int ks = 0; ks < 2; ++ks) {       // BK=128: two rounds
#pragma unroll
    for (int i = 0; i < 16; ++i) {
      int ch = w * 16 + i;               // 0..63, uniform per wave
      bool isA = ch < 32;
      int ct = isA ? ch : ch - 32;       // chunk 0..31
      int rowc = ct * 4 + rloc4;         // row within 128-tile
      int ss = slot ^ (rowc & 7);        // pre-swizzled source slot
      const ushort* src = (isA ? arow_base : brow_base)
                          + (size_t)rowc * DDIM + ks * 128 + ss * 8;
      char* ldsb = (char*)(isA ? Ab : Bb) + ct * 1024;   // uniform base
      async_copy16(ldsb, src);
    }
    __syncthreads();                     // drains vmcnt (compiler)
#pragma unroll
    for (int kk = 0; kk < 4; ++kk) {
      short8 af[4], bf[4];
#pragma unroll
      for (int m = 0; m < 4; ++m) {
        int arow = wm * 64 + m * 16 + cl;
        int ab = arow * 256 + (((kk * 4 + g) ^ (arow & 7)) << 4);
        af[m] = *reinterpret_cast<const short8*>((char*)Ab + ab);
      }
#pragma unroll
      for (int n = 0; n < 4; ++n) {
        int brow = wn * 64 + n * 16 + cl;
        int bb = brow * 256 + (((kk * 4 + g) ^ (brow & 7)) << 4);
        bf[n] = *reinterpret_cast<const short8*>((char*)Bb + bb);
      }
#pragma unroll
      for (int m = 0; m < 4; ++m)
#pragma unroll
        for (int n = 0; n < 4; ++n)
          acc[m][n] = __builtin_amdgcn_mfma_f32_16x16x32_bf16(af[m], bf[n], acc[m][n], 0, 0, 0);
    }
    __syncthreads();
  }

  // epilogue: C/D layout col=lane&15, row=(lane>>4)*4+j  [m89/m91]
  int col_base = nt * 128 + wn * 64;
  int row_base = mt * 128 + wm * 64;
  float e2v[4];
#pragma unroll
  for (int n = 0; n < 4; ++n) e2v[n] = e2f[col_base + n * 16 + cl];

#pragma unroll
  for (int m = 0; m < 4; ++m) {
#pragma unroll
    for (int j = 0; j < 4; ++j) {
      int row = row_base + m * 16 + g * 4 + j;
      if (PHASE == 1) {
        float mn = INFINITY;
#pragma unroll
        for (int n = 0; n < 4; ++n) {
          float s = __fsub_rn(e2v[n], __fmul_rn(2.0f, acc[m][n][j]));
          mn = fminf(mn, s);
        }
#pragma unroll
        for (int off = 1; off < 16; off <<= 1)
          mn = fminf(mn, __shfl_xor(mn, off));
        if (cl == 0) atomicMin(&rowMinU[row], fmap(mn));   // fire-and-forget
      } else {
        float thr = funmap(rowMinU[row]) + MARGIN;         // FINAL min: race-free
#pragma unroll
        for (int n = 0; n < 4; ++n) {
          float s = __fsub_rn(e2v[n], __fmul_rn(2.0f, acc[m][n][j]));
          if (s <= thr) {
            unsigned sl = atomicAdd(&cnt[row], 1u);
            if (sl < CAP) cand[row * CAP + sl] = col_base + n * 16 + cl;
          }
        }
      }
    }
  }
}

// Fused: exact fp32-chain rescore (lex (s,idx) min = first-min-wins) + overflow
// full-scan fallback + gather + per-row loss partial. r2 computed inline.
// Chain loads float4-vectorized (same IEEE order: x,y,z,w sequential FMAs).
__global__ __launch_bounds__(256) void k_rescore_gather(const float* __restrict__ z,
                                                        const float* __restrict__ cb,
                                                        const float* __restrict__ e2f,
                                                        const unsigned* __restrict__ cnt,
                                                        const int* __restrict__ cand,
                                                        float* __restrict__ out_q,
                                                        float* __restrict__ out_idx,
                                                        float* __restrict__ lpart) {
  int t = threadIdx.x, w = t >> 6, lane = t & 63;
  int row = blockIdx.x * 4 + w;
  const float* xp = z + (size_t)row * DDIM;
  const float4* xp4 = reinterpret_cast<const float4*>(xp);
  float4 x4 = xp4[lane];
  double rd = (double)x4.x * x4.x + (double)x4.y * x4.y + (double)x4.z * x4.z + (double)x4.w * x4.w;
#pragma unroll
  for (int off = 1; off < 64; off <<= 1) rd += __shfl_xor(rd, off);
  float r2v = (float)rd;                  // same summation as r6's k_prep (validated)

  unsigned n = cnt[row];
  float s = INFINITY; int ci = 0x7fffffff;
  if (n <= CAP) {
    if (lane < (int)n) {                  // CAP=56 < 64: single pass
      ci = cand[row * CAP + lane];
      const float4* ep4 = reinterpret_cast<const float4*>(cb + (size_t)ci * DDIM);
      float acc = 0.f;
#pragma unroll 4
      for (int k4 = 0; k4 < 64; ++k4) {   // k ascending, exact chain order
        float4 e = ep4[k4], x = xp4[k4];
        acc = __fmaf_rn(x.x, e.x, acc);
        acc = __fmaf_rn(x.y, e.y, acc);
        acc = __fmaf_rn(x.z, e.z, acc);
        acc = __fmaf_rn(x.w, e.w, acc);
      }
      s = __fsub_rn(__fadd_rn(r2v, e2f[ci]), __fmul_rn(2.0f, acc));
    }
  } else {
    for (int base = 0; base < KCW; base += 64) {   // exact full-scan fallback
      int c = base + lane;
      const float4* ep4 = reinterpret_cast<const float4*>(cb + (size_t)c * DDIM);
      float acc = 0.f;
#pragma unroll 4
      for (int k4 = 0; k4 < 64; ++k4) {
        float4 e = ep4[k4], x = xp4[k4];
        acc = __fmaf_rn(x.x, e.x, acc);
        acc = __fmaf_rn(x.y, e.y, acc);
        acc = __fmaf_rn(x.z, e.z, acc);
        acc = __fmaf_rn(x.w, e.w, acc);
      }
      float scv = __fsub_rn(__fadd_rn(r2v, e2f[c]), __fmul_rn(2.0f, acc));
      if (scv < s) { s = scv; ci = c; }            // c ascending: first-wins
    }
  }
#pragma unroll
  for (int off = 1; off < 64; off <<= 1) {         // butterfly: all lanes get min
    float os = __shfl_xor(s, off); int oi = __shfl_xor(ci, off);
    if (os < s || (os == s && oi < ci)) { s = os; ci = oi; }
  }
  if (lane == 0) out_idx[row] = (float)ci;

  float4 qv = *reinterpret_cast<const float4*>(cb + (size_t)ci * DDIM + lane * 4);
  float* o = out_q + (size_t)row * DDIM + lane * 4; // out+1 base: scalar stores
  o[0] = qv.x; o[1] = qv.y; o[2] = qv.z; o[3] = qv.w;
  float dx = qv.x - x4.x, dy = qv.y - x4.y, dz = qv.z - x4.z, dw = qv.w - x4.w;
  double d = (double)dx * dx + (double)dy * dy + (double)dz * dz + (double)dw * dw;
#pragma unroll
  for (int off = 1; off < 64; off <<= 1) d += __shfl_xor(d, off);
  if (lane == 0) lpart[row] = (float)d;
}

__global__ __launch_bounds__(256) void k_loss(const float* __restrict__ lpart,
                                              float* __restrict__ out0) {
  __shared__ double red[256];
  int t = threadIdx.x;
  double s = 0.0;
  for (int j = t; j < NROWS; j += 256) s += lpart[j];  // fixed order -> deterministic
  red[t] = s;
  __syncthreads();
  for (int off = 128; off > 0; off >>= 1) {
    if (t < off) red[t] += red[t + off];
    __syncthreads();
  }
  if (t == 0) out0[0] = (float)(1.25 * red[0] / (double)((size_t)NROWS * DDIM));
}

extern "C" void kernel_launch(void* const* d_in, const int* in_sizes, int n_in,
                              void* d_out, int out_size, void* d_ws, size_t ws_size,
                              hipStream_t stream) {
  const float* z  = (const float*)d_in[0];   // [16,512,256] flat
  const float* cb = (const float*)d_in[1];   // [8192,256]
  float* out = (float*)d_out;
  char* ws = (char*)d_ws;
  const size_t HALF = (size_t)NROWS * DDIM;  // 2,097,152

  // bf16 copies in the out_q region (out+4 floats: 16B-aligned). Last 3 floats
  // of cbb overlap out_idx[0..2]; out_idx is written by k_rescore_gather, which
  // runs after the last zb/cbb read (k_score<2>). Recomputed every call.
  ushort* zb  = (ushort*)(out + 4);
  ushort* cbb = zb + HALF;

  // ws: e2f 32K | cnt 32K | rowMinU 32K (lpart overlays it after k_score<2>) |
  //     cand int 8192*56*4 = 1.75MB ; total ~1.85MB (< 2,211,840 proven in r2)
  size_t off = 0;
  float*    e2f     = (float*)(ws + off);    off += NROWS * 4;
  unsigned* cnt     = (unsigned*)(ws + off); off += NROWS * 4;
  unsigned* rowMinU = (unsigned*)(ws + off);
  float*    lpart   = (float*)(ws + off);    off += NROWS * 4;   // overlays rowMinU
  int*      cand    = (int*)(ws + off);      off += (size_t)NROWS * CAP * 4;

  float* out_q   = out + 1;
  float* out_idx = out + 1 + HALF;

  k_prep_cast     <<<(2 * NROWS) / 4, 256, 0, stream>>>(z, cb, zb, cbb, e2f, rowMinU, cnt);
  k_score<1>      <<<64 * 64,         256, 0, stream>>>(zb, cbb, e2f, rowMinU, cnt, cand);
  k_score<2>      <<<64 * 64,         256, 0, stream>>>(zb, cbb, e2f, rowMinU, cnt, cand);
  k_rescore_gather<<<NROWS / 4,       256, 0, stream>>>(z, cb, e2f, cnt, cand, out_q, out_idx, lpart);
  k_loss          <<<1,               256, 0, stream>>>(lpart, out);
}